// Round 13
// baseline (2168.708 us; speedup 1.0000x reference)
//
#include <hip/hip_runtime.h>
#include <hip/hip_fp16.h>

using uint = unsigned int;

static constexpr int NN   = 100000;  // nodes
static constexpr int NE   = 1600000; // edges per set
static constexpr int DIM  = 64;
static constexpr int HH   = 32;
static constexpr int HB   = 256;               // partition chunks per edge set
static constexpr int CHUNK = NE / HB;          // 6250 (exact)
static constexpr int BSH  = 8;                 // bucket = dst >> 8 (256 nodes/bucket)
static constexpr int BSZ  = 256;
static constexpr int NBIN = 512;               // bins (391 live)
static constexpr int NBKT = (NN + BSZ - 1) / BSZ;  // 391
static constexpr int NBLK = (NN + 255) / 256;  // 391 node-blocks

__device__ __forceinline__ float2 up16(uint v) {
  __half2 h = *reinterpret_cast<__half2*>(&v);
  return __half22float2(h);
}
__device__ __forceinline__ uint pk16(float a, float b) {
  __half2 h = __floats2half2_rn(a, b);
  return *reinterpret_cast<uint*>(&h);
}

// ================= atomic-free bucket partition (by dst>>8; NO CSR needed) ==========

// A1: per-chunk 512-bin histogram. part_hist[set][chunk][bin]
__global__ void c_hist(const int* __restrict__ pe, const int* __restrict__ ne,
                       int* __restrict__ part_hist) {
  const int set = blockIdx.y;
  const int* dstA = (set ? ne : pe) + NE;
  __shared__ int h[NBIN];
  h[threadIdx.x] = 0; h[threadIdx.x + 256] = 0;
  __syncthreads();
  int lo = blockIdx.x * CHUNK;
  int hi = lo + CHUNK;
  for (int i = lo + threadIdx.x; i < hi; i += 256)
    atomicAdd(&h[dstA[i] >> BSH], 1);
  __syncthreads();
  int* o = part_hist + (size_t)(set * HB + blockIdx.x) * NBIN;
  o[threadIdx.x] = h[threadIdx.x];
  o[threadIdx.x + 256] = h[threadIdx.x + 256];
}

// A2: per (set,bin): exclusive scan over HB chunk-partials (in place); total->tot.
__global__ void c_colscan(int* __restrict__ part_hist, int* __restrict__ tot) {
  const int set = blockIdx.y;
  const int k   = blockIdx.x;   // bin 0..511
  const int t   = threadIdx.x;  // chunk 0..255
  int v = part_hist[(size_t)(set * HB + t) * NBIN + k];
  __shared__ int sm[256];
  sm[t] = v;
  __syncthreads();
  for (int off = 1; off < 256; off <<= 1) {
    int add = (t >= off) ? sm[t - off] : 0;
    __syncthreads();
    sm[t] += add;
    __syncthreads();
  }
  part_hist[(size_t)(set * HB + t) * NBIN + k] = (t == 0) ? 0 : sm[t - 1];
  if (t == 255) tot[set * NBIN + k] = sm[255];
}

// A3: one block, 1024 threads: exclusive scan of 512 bins per set -> base[set][0..512]
__global__ void c_basescan(const int* __restrict__ tot, int* __restrict__ base) {
  const int t   = threadIdx.x;
  const int seg = t >> 9;      // set
  const int idx = t & 511;     // bin
  int v = tot[seg * NBIN + idx];
  __shared__ int sm[1024];
  sm[t] = v;
  __syncthreads();
  for (int off = 1; off < 512; off <<= 1) {
    int add = (idx >= off) ? sm[t - off] : 0;
    __syncthreads();
    sm[t] += add;
    __syncthreads();
  }
  base[seg * (NBIN + 1) + idx] = (idx == 0) ? 0 : sm[t - 1];
  if (idx == 511) base[seg * (NBIN + 1) + 512] = sm[t];   // == NE
}

// A4: scatter packed (src<<8 | dst&255) into bucket-partitioned order.
__global__ void c_scatter(const int* __restrict__ pe, const int* __restrict__ ne,
                          const int* __restrict__ part_hist, const int* __restrict__ base,
                          uint* __restrict__ partP, uint* __restrict__ partN) {
  const int set = blockIdx.y;
  const int b   = blockIdx.x;
  const int* srcA = set ? ne : pe;
  const int* dstA = srcA + NE;
  uint* part = set ? partN : partP;
  __shared__ int off[NBIN];
  const int* ph = part_hist + (size_t)(set * HB + b) * NBIN;
  off[threadIdx.x]       = base[set * (NBIN + 1) + threadIdx.x]       + ph[threadIdx.x];
  off[threadIdx.x + 256] = base[set * (NBIN + 1) + threadIdx.x + 256] + ph[threadIdx.x + 256];
  __syncthreads();
  int lo = b * CHUNK;
  int hi = lo + CHUNK;
  for (int i = lo + threadIdx.x; i < hi; i += 256) {
    int src = srcA[i];
    int dst = dstA[i];
    int pos = atomicAdd(&off[dst >> BSH], 1);
    part[pos] = ((uint)src << BSH) | (uint)(dst & (BSZ - 1));
  }
}

// ---------------- layer-1 pre-transform (standalone) ----------------
// y1u[node] = 32 uints: [pos half 0..15 | neg half 16..31] (f16); r1 = x@wr+b (in d_out)
__global__ void k_pre1(const float* __restrict__ x,
                       const float* __restrict__ w1_pl, const float* __restrict__ w1_pr,
                       const float* __restrict__ b1_p,
                       const float* __restrict__ w1_nl, const float* __restrict__ w1_nr,
                       const float* __restrict__ b1_n,
                       uint* __restrict__ y1u, float* __restrict__ r1) {
  const int h = blockIdx.y;
  const float* wl   = h ? w1_nl : w1_pl;  // [64][32]
  const float* wr   = h ? w1_nr : w1_pr;  // [64][32]
  const float* bias = h ? b1_n  : b1_p;

  __shared__ float s_wl[DIM * HH];
  __shared__ float s_wr[DIM * HH];
  for (int i = threadIdx.x; i < DIM * HH; i += 256) {
    s_wl[i] = wl[i];
    s_wr[i] = wr[i];
  }
  __syncthreads();

  int node = blockIdx.x * 256 + threadIdx.x;
  if (node >= NN) return;

  float ay[HH], ar[HH];
#pragma unroll
  for (int j = 0; j < HH; ++j) { ay[j] = 0.f; ar[j] = bias[j]; }

  const float4* xrow = (const float4*)(x + (size_t)node * DIM);
#pragma unroll 4
  for (int k4 = 0; k4 < DIM / 4; ++k4) {
    float4 xv = xrow[k4];
#pragma unroll
    for (int u = 0; u < 4; ++u) {
      int k = k4 * 4 + u;
      float xk = (&xv.x)[u];
#pragma unroll
      for (int j = 0; j < HH; ++j) {
        ay[j] += xk * s_wl[k * HH + j];
        ar[j] += xk * s_wr[k * HH + j];
      }
    }
  }

  uint*  yo = y1u + (size_t)node * 32 + h * 16;
  float* ro = r1 + (size_t)node * 64 + h * 32;
#pragma unroll
  for (int j = 0; j < 16; ++j) yo[j] = pk16(ay[2 * j], ay[2 * j + 1]);
#pragma unroll
  for (int j = 0; j < HH; ++j) ro[j] = ar[j];
}

// ---------------- bucket-centric aggregation 1 (NO CSR) ----------------
// Block = bucket k (256 nodes). For half in {pos,neg}: stream the bucket's packed
// pairs, gather y1u[src] half-row, atomicAdd into LDS acc[256][32] (stride 33 to
// spread banks) + count; finalize z[:,half*32..] = relu(acc/max(cnt,1) + r1).
// NOTE: r1 and z ALIAS (both d_out): same-thread read-then-write per element.
__global__ __launch_bounds__(1024) void k_aggr1B(
    const uint* __restrict__ y1u,
    const uint* __restrict__ partP, const uint* __restrict__ partN,
    const int* __restrict__ base,
    const float* r1, float* z) {
  __shared__ float acc[BSZ * 33];
  __shared__ int cnt[BSZ];
  const int k = blockIdx.x;
  const int t = threadIdx.x;
  const int slot = t >> 2;      // edge slot 0..255
  const int f = t & 3;          // uint4 idx within 16-uint half
  const int nbase = k * BSZ;

  for (int half = 0; half < 2; ++half) {
    const uint* part = half ? partN : partP;
    const int s = base[half * (NBIN + 1) + k];
    const int e = base[half * (NBIN + 1) + k + 1];

    for (int w = t; w < BSZ * 33; w += 1024) acc[w] = 0.f;
    if (t < BSZ) cnt[t] = 0;
    __syncthreads();

    for (int i0 = s; i0 < e; i0 += 256) {
      int i = i0 + slot;
      if (i < e) {
        uint p = part[i];
        int src = (int)(p >> BSH);
        int dl  = (int)(p & (BSZ - 1));
        uint4 v = *(const uint4*)&y1u[(size_t)src * 32 + half * 16 + 4 * f];
        float2 p0 = up16(v.x), p1 = up16(v.y), p2 = up16(v.z), p3 = up16(v.w);
        float* a = acc + dl * 33 + 8 * f;
        atomicAdd(a + 0, p0.x); atomicAdd(a + 1, p0.y);
        atomicAdd(a + 2, p1.x); atomicAdd(a + 3, p1.y);
        atomicAdd(a + 4, p2.x); atomicAdd(a + 5, p2.y);
        atomicAdd(a + 6, p3.x); atomicAdd(a + 7, p3.y);
        if (f == 0) atomicAdd(&cnt[dl], 1);
      }
    }
    __syncthreads();

    {
      int n = t >> 2, q = t & 3;          // node-local, feat group (8 feats)
      int ng = nbase + n;
      if (ng < NN) {
        float inv = 1.f / (float)max(cnt[n], 1);
        size_t gb = (size_t)ng * 64 + half * 32 + 8 * q;
        const float* a = acc + n * 33 + 8 * q;
        float4 r0 = *(const float4*)(r1 + gb);
        float4 r1v = *(const float4*)(r1 + gb + 4);
        float4 o0, o1;
        o0.x = fmaxf(a[0] * inv + r0.x, 0.f);
        o0.y = fmaxf(a[1] * inv + r0.y, 0.f);
        o0.z = fmaxf(a[2] * inv + r0.z, 0.f);
        o0.w = fmaxf(a[3] * inv + r0.w, 0.f);
        o1.x = fmaxf(a[4] * inv + r1v.x, 0.f);
        o1.y = fmaxf(a[5] * inv + r1v.y, 0.f);
        o1.z = fmaxf(a[6] * inv + r1v.z, 0.f);
        o1.w = fmaxf(a[7] * inv + r1v.w, 0.f);
        *(float4*)(z + gb) = o0;
        *(float4*)(z + gb + 4) = o1;
      }
    }
    __syncthreads();
  }
}

// ---------------- pre-transform layer 2 (unchanged) ----------------
__global__ void k_mid(const float* __restrict__ z,
                      const float* __restrict__ w2_pl, const float* __restrict__ w2_pr,
                      const float* __restrict__ b2_p,
                      const float* __restrict__ w2_nl, const float* __restrict__ w2_nr,
                      const float* __restrict__ b2_n,
                      uint* __restrict__ u_pos, uint* __restrict__ u_neg,
                      float* __restrict__ r2) {
  const int t = blockIdx.y;
  const float* mat;
  const float* bias = nullptr;
  int srcHalf;            // 0 = zp, 1 = zn
  switch (t) {
    case 0: mat = w2_pl;            srcHalf = 0; break;
    case 1: mat = w2_nl;            srcHalf = 1; break;
    case 2: mat = w2_pl + 32 * 32;  srcHalf = 1; break;
    case 3: mat = w2_nl + 32 * 32;  srcHalf = 0; break;
    case 4: mat = w2_pr; bias = b2_p; srcHalf = 0; break;
    default: mat = w2_nr; bias = b2_n; srcHalf = 1; break;
  }

  __shared__ float s_m[HH][HH];
  for (int i = threadIdx.x; i < HH * HH; i += 256) s_m[i >> 5][i & 31] = mat[i];
  __syncthreads();

  int node = blockIdx.x * 256 + threadIdx.x;
  if (node >= NN) return;

  float acc[HH];
#pragma unroll
  for (int j = 0; j < HH; ++j) acc[j] = bias ? bias[j] : 0.f;

  const float4* zrow = (const float4*)(z + (size_t)node * 64 + srcHalf * 32);
#pragma unroll 4
  for (int k4 = 0; k4 < HH / 4; ++k4) {
    float4 v = zrow[k4];
#pragma unroll
    for (int u = 0; u < 4; ++u) {
      int k = k4 * 4 + u;
      float vv = (&v.x)[u];
#pragma unroll
      for (int j = 0; j < HH; ++j) acc[j] += vv * s_m[k][j];
    }
  }

  if (t < 4) {
    uint* o = (t < 2 ? u_pos : u_neg) + (size_t)node * 32 + (t & 1) * 16;
#pragma unroll
    for (int j = 0; j < 16; ++j) o[j] = pk16(acc[2 * j], acc[2 * j + 1]);
  } else {
    float* o = r2 + (size_t)node * 64 + (t - 4) * 32;
#pragma unroll
    for (int j = 0; j < HH; ++j) o[j] = acc[j];
  }
}

// ---------------- bucket-centric aggregation 2 (NO CSR) ----------------
// Block = bucket k. Phase P: stream pos pairs, gather u_pos rows (128B), unscaled
// atomicAdd into acc[256][64] (stride 65) + cntP. Count cntN (pairs only). Scale
// acc by invP. Phase N: stream neg pairs, gather u_neg, atomicAdd pre-scaled by
// invN. Final: out = relu(acc + r2).
__global__ __launch_bounds__(1024) void k_aggr2B(
    const uint* __restrict__ u_pos, const uint* __restrict__ u_neg,
    const uint* __restrict__ partP, const uint* __restrict__ partN,
    const int* __restrict__ base,
    const float* __restrict__ r2, float* __restrict__ out) {
  __shared__ float acc[BSZ * 65];
  __shared__ int cntP[BSZ], cntN[BSZ];
  __shared__ float sinvP[BSZ], sinvN[BSZ];
  const int k = blockIdx.x;
  const int t = threadIdx.x;
  const int slot = t >> 3;   // edge slot 0..127
  const int f = t & 7;       // uint4 idx in 32-uint row
  const int nbase = k * BSZ;
  const int sP = base[k],              eP = base[k + 1];
  const int sN = base[(NBIN + 1) + k], eN = base[(NBIN + 1) + k + 1];

  for (int w = t; w < BSZ * 65; w += 1024) acc[w] = 0.f;
  if (t < BSZ) { cntP[t] = 0; cntN[t] = 0; }
  __syncthreads();

  // phase P: pos gather (unscaled) + cntP
  for (int i0 = sP; i0 < eP; i0 += 128) {
    int i = i0 + slot;
    if (i < eP) {
      uint p = partP[i];
      int src = (int)(p >> BSH);
      int dl  = (int)(p & (BSZ - 1));
      uint4 v = *(const uint4*)&u_pos[(size_t)src * 32 + 4 * f];
      float2 p0 = up16(v.x), p1 = up16(v.y), p2 = up16(v.z), p3 = up16(v.w);
      float* a = acc + dl * 65 + 8 * f;
      atomicAdd(a + 0, p0.x); atomicAdd(a + 1, p0.y);
      atomicAdd(a + 2, p1.x); atomicAdd(a + 3, p1.y);
      atomicAdd(a + 4, p2.x); atomicAdd(a + 5, p2.y);
      atomicAdd(a + 6, p3.x); atomicAdd(a + 7, p3.y);
      if (f == 0) atomicAdd(&cntP[dl], 1);
    }
  }
  // neg count-only (pairs, no gather)
  for (int i = sN + t; i < eN; i += 1024)
    atomicAdd(&cntN[partN[i] & (BSZ - 1)], 1);
  __syncthreads();

  if (t < BSZ) {
    sinvP[t] = 1.f / (float)max(cntP[t], 1);
    sinvN[t] = 1.f / (float)max(cntN[t], 1);
  }
  __syncthreads();

  // scale acc by invP
  for (int w = t; w < BSZ * 64; w += 1024) {
    int n = w >> 6, ff = w & 63;
    acc[n * 65 + ff] *= sinvP[n];
  }
  __syncthreads();

  // phase N: neg gather pre-scaled by invN
  for (int i0 = sN; i0 < eN; i0 += 128) {
    int i = i0 + slot;
    if (i < eN) {
      uint p = partN[i];
      int src = (int)(p >> BSH);
      int dl  = (int)(p & (BSZ - 1));
      float sc = sinvN[dl];
      uint4 v = *(const uint4*)&u_neg[(size_t)src * 32 + 4 * f];
      float2 p0 = up16(v.x), p1 = up16(v.y), p2 = up16(v.z), p3 = up16(v.w);
      float* a = acc + dl * 65 + 8 * f;
      atomicAdd(a + 0, p0.x * sc); atomicAdd(a + 1, p0.y * sc);
      atomicAdd(a + 2, p1.x * sc); atomicAdd(a + 3, p1.y * sc);
      atomicAdd(a + 4, p2.x * sc); atomicAdd(a + 5, p2.y * sc);
      atomicAdd(a + 6, p3.x * sc); atomicAdd(a + 7, p3.y * sc);
    }
  }
  __syncthreads();

  // out = relu(acc + r2)
  {
    int n = t >> 2, q = t & 3;          // 16 feats per thread
    int ng = nbase + n;
    if (ng < NN) {
      size_t gb = (size_t)ng * 64 + 16 * q;
      const float* a = acc + n * 65 + 16 * q;
#pragma unroll
      for (int j4 = 0; j4 < 4; ++j4) {
        float4 r = *(const float4*)(r2 + gb + 4 * j4);
        float4 o;
        o.x = fmaxf(a[4 * j4 + 0] + r.x, 0.f);
        o.y = fmaxf(a[4 * j4 + 1] + r.y, 0.f);
        o.z = fmaxf(a[4 * j4 + 2] + r.z, 0.f);
        o.w = fmaxf(a[4 * j4 + 3] + r.w, 0.f);
        *(float4*)(out + gb + 4 * j4) = o;
      }
    }
  }
}

// ---------------- launch ----------------

extern "C" void kernel_launch(void* const* d_in, const int* in_sizes, int n_in,
                              void* d_out, int out_size, void* d_ws, size_t ws_size,
                              hipStream_t stream) {
  const float* x     = (const float*)d_in[0];
  const int*   pe    = (const int*)d_in[1];
  const int*   ne    = (const int*)d_in[2];
  const float* w1_pl = (const float*)d_in[3];
  const float* w1_pr = (const float*)d_in[4];
  const float* b1_p  = (const float*)d_in[5];
  const float* w1_nl = (const float*)d_in[6];
  const float* w1_nr = (const float*)d_in[7];
  const float* b1_n  = (const float*)d_in[8];
  const float* w2_pl = (const float*)d_in[9];
  const float* w2_pr = (const float*)d_in[10];
  const float* b2_p  = (const float*)d_in[11];
  const float* w2_nl = (const float*)d_in[12];
  const float* w2_nr = (const float*)d_in[13];
  const float* b2_n  = (const float*)d_in[14];

  char* ws = (char*)d_ws;
  size_t off = 0;
  auto alloc = [&](size_t bytes) -> char* {
    char* p = ws + off;
    off = (off + bytes + 255) & ~(size_t)255;
    return p;
  };

  int* tot  = (int*)alloc((size_t)2 * NBIN * 4);
  int* base = (int*)alloc((size_t)2 * (NBIN + 1) * 4);

  // packed pair arrays: live c_scatter .. k_aggr2B (12.8MB)
  uint* partP = (uint*)alloc((size_t)NE * 4);
  uint* partN = (uint*)alloc((size_t)NE * 4);

  // union region U (25.6MB): part_hist (1MB, hist..scatter) / u_pos+u_neg (mid..aggr2B)
  char* regU = alloc((size_t)NN * 64 * 4);
  int*  part_hist = (int*)regU;                      // 2*HB*NBIN*4 = 1MB
  uint* u_pos = (uint*)regU;
  uint* u_neg = (uint*)(regU + (size_t)NN * 32 * 4);

  // union region B (25.6MB): y1u (pre1..aggr1B, 12.8MB) / r2 (mid..aggr2B)
  char*  regB = alloc((size_t)NN * 64 * 4);
  uint*  y1u  = (uint*)regB;
  float* r2   = (float*)regB;

  // r1 and z both live in d_out; k_aggr2B fully overwrites d_out at the end.
  float* r1 = (float*)d_out;
  float* z  = (float*)d_out;

  dim3 pg(NBLK, 2);
  k_pre1<<<pg, 256, 0, stream>>>(x, w1_pl, w1_pr, b1_p, w1_nl, w1_nr, b1_n,
                                 y1u, r1);

  dim3 hg(HB, 2);
  c_hist<<<hg, 256, 0, stream>>>(pe, ne, part_hist);
  dim3 cg(NBIN, 2);
  c_colscan<<<cg, 256, 0, stream>>>(part_hist, tot);
  c_basescan<<<1, 1024, 0, stream>>>(tot, base);
  c_scatter<<<hg, 256, 0, stream>>>(pe, ne, part_hist, base, partP, partN);

  k_aggr1B<<<NBKT, 1024, 0, stream>>>(y1u, partP, partN, base, r1, z);

  dim3 g2(NBLK, 6);
  k_mid<<<g2, 256, 0, stream>>>(z, w2_pl, w2_pr, b2_p, w2_nl, w2_nr, b2_n,
                                u_pos, u_neg, r2);

  k_aggr2B<<<NBKT, 1024, 0, stream>>>(u_pos, u_neg, partP, partN, base, r2,
                                      (float*)d_out);
}

// Round 15
// 298.521 us; speedup vs baseline: 7.2648x; 7.2648x over previous
//
#include <hip/hip_runtime.h>
#include <hip/hip_fp16.h>

using uint = unsigned int;

static constexpr int NN  = 100000;   // nodes
static constexpr int NE  = 1600000;  // edges per set
static constexpr int DIM = 64;
static constexpr int HH  = 32;
static constexpr int NBLK = (NN + 511) / 512;   // 196 pre1 node-blocks (512 nodes each)
static constexpr int HB   = 256;                // partition chunks per edge set
static constexpr int CHUNK = NE / HB;           // 6250 (exact)
static constexpr int BSH  = 9;                  // bucket = dst >> 9 (512 nodes/bucket)
static constexpr int BSZ  = 512;
static constexpr int NBKT = (NN + BSZ - 1) / BSZ;  // 196 live buckets (of 256 bins)

__device__ __forceinline__ float2 up16(uint v) {
  __half2 h = *reinterpret_cast<__half2*>(&v);
  return __half22float2(h);
}
__device__ __forceinline__ uint pk16(float a, float b) {
  __half2 h = __floats2half2_rn(a, b);
  return *reinterpret_cast<uint*>(&h);
}

// ================= atomic-free CSR build (radix partition by dst>>9) =================
// R6-proven shapes: 256 chunks x 256 bins; scatter runs ~32 edges (~128B) per (chunk,bin).

// A1: per-chunk 256-bin histogram. part_hist[set][chunk][bin]
__global__ void c_hist(const int* __restrict__ pe, const int* __restrict__ ne,
                       int* __restrict__ part_hist) {
  const int set = blockIdx.y;
  const int* dstA = (set ? ne : pe) + NE;
  __shared__ int h[256];
  h[threadIdx.x] = 0;
  __syncthreads();
  int lo = blockIdx.x * CHUNK;
  int hi = lo + CHUNK;
  for (int i = lo + threadIdx.x; i < hi; i += 256)
    atomicAdd(&h[dstA[i] >> BSH], 1);
  __syncthreads();
  part_hist[(size_t)(set * HB + blockIdx.x) * 256 + threadIdx.x] = h[threadIdx.x];
}

// A2: per (set,bin): exclusive scan over the HB chunk-partials (in place); total->tot.
__global__ void c_colscan(int* __restrict__ part_hist, int* __restrict__ tot) {
  const int set = blockIdx.y;
  const int k   = blockIdx.x;   // bin 0..255
  const int t   = threadIdx.x;  // chunk 0..255
  int v = part_hist[(size_t)(set * HB + t) * 256 + k];
  __shared__ int sm[256];
  sm[t] = v;
  __syncthreads();
  for (int off = 1; off < 256; off <<= 1) {
    int add = (t >= off) ? sm[t - off] : 0;
    __syncthreads();
    sm[t] += add;
    __syncthreads();
  }
  part_hist[(size_t)(set * HB + t) * 256 + k] = (t == 0) ? 0 : sm[t - 1];
  if (t == 255) tot[set * 256 + k] = sm[255];
}

// A3: one block, 512 threads: exclusive scan of 256 bins per set -> base[set][0..256]
__global__ void c_basescan(const int* __restrict__ tot, int* __restrict__ base) {
  const int t   = threadIdx.x;
  const int seg = t >> 8;      // set
  const int idx = t & 255;     // bin
  int v = tot[seg * 256 + idx];
  __shared__ int sm[512];
  sm[t] = v;
  __syncthreads();
  for (int off = 1; off < 256; off <<= 1) {
    int add = (idx >= off) ? sm[t - off] : 0;
    __syncthreads();
    sm[t] += add;
    __syncthreads();
  }
  base[seg * 257 + idx] = (idx == 0) ? 0 : sm[t - 1];
  if (idx == 255) base[seg * 257 + 256] = sm[t];   // == NE
}

// A4: scatter packed (src<<9 | dst&511) into bucket-partitioned order.
// LDS counters start at the chunk's reserved absolute offset per bin -> no global atomics.
__global__ void c_scatter(const int* __restrict__ pe, const int* __restrict__ ne,
                          const int* __restrict__ part_hist, const int* __restrict__ base,
                          uint* __restrict__ partP, uint* __restrict__ partN) {
  const int set = blockIdx.y;
  const int b   = blockIdx.x;
  const int* srcA = set ? ne : pe;
  const int* dstA = srcA + NE;
  uint* part = set ? partN : partP;
  __shared__ int off[256];
  const int* ph = part_hist + (size_t)(set * HB + b) * 256;
  off[threadIdx.x] = base[set * 257 + threadIdx.x] + ph[threadIdx.x];
  __syncthreads();
  int lo = b * CHUNK;
  int hi = lo + CHUNK;
  for (int i = lo + threadIdx.x; i < hi; i += 256) {
    int src = srcA[i];
    int dst = dstA[i];
    int pos = atomicAdd(&off[dst >> BSH], 1);
    part[pos] = ((uint)src << BSH) | (uint)(dst & (BSZ - 1));
  }
}

// B (+pre1 fused, 512 threads, LDS UNIONED at 16KB):
// Blocks [0, 2*NBKT): per-bucket CSR (count -> scan -> rowptr + col scatter).
// Blocks [2*NBKT, 2*NBKT+2*NBLK): layer-1 pre-transform, 512 nodes per block.
__global__ void c_bucket(const uint* __restrict__ partP, const uint* __restrict__ partN,
                         const int* __restrict__ base,
                         int* __restrict__ row_p, int* __restrict__ row_n,
                         int* __restrict__ col_p, int* __restrict__ col_n,
                         const float* __restrict__ x,
                         const float* __restrict__ w1_pl, const float* __restrict__ w1_pr,
                         const float* __restrict__ b1_p,
                         const float* __restrict__ w1_nl, const float* __restrict__ w1_nr,
                         const float* __restrict__ b1_n,
                         uint* __restrict__ y1u, float* __restrict__ r1) {
  __shared__ uint smem[4096];   // 16KB union: bucket uses 6KB, pre1 uses 16KB
  const int bx = blockIdx.x;
  const int t  = threadIdx.x;   // 0..511

  if (bx < 2 * NBKT) {
    // ---- bucket-CSR path (512 threads: 16 trips over ~8200 edges) ----
    const int set = (bx >= NBKT) ? 1 : 0;
    const int k   = bx - (set ? NBKT : 0);
    const uint* part = set ? partN : partP;
    int* row = set ? row_n : row_p;
    int* col = set ? col_n : col_p;
    const int lo = k * BSZ;
    const int hi = min(lo + BSZ, NN);
    const int s = base[set * 257 + k];
    const int e = base[set * 257 + k + 1];

    int* cnt  = (int*)smem;          // [512]
    int* rowl = (int*)smem + 512;    // [512]
    int* cnt2 = (int*)smem + 1024;   // [512]
    cnt[t] = 0; cnt2[t] = 0;
    __syncthreads();
    for (int i = s + t; i < e; i += 512)
      atomicAdd(&cnt[part[i] & (BSZ - 1)], 1);
    __syncthreads();
    rowl[t] = cnt[t];
    __syncthreads();
    for (int off = 1; off < BSZ; off <<= 1) {
      int a0 = (t >= off) ? rowl[t - off] : 0;
      __syncthreads();
      rowl[t] += a0;
      __syncthreads();
    }
    if (lo + t < hi) row[lo + t] = s + (t ? rowl[t - 1] : 0);
    if (k == NBKT - 1 && t == 0) row[NN] = NE;
    for (int i = s + t; i < e; i += 512) {
      uint p = part[i];
      int l = p & (BSZ - 1);
      int pos = s + (l ? rowl[l - 1] : 0) + atomicAdd(&cnt2[l], 1);
      col[pos] = (int)(p >> BSH);
    }
    return;
  }

  // ---- pre1 path: y1 = x@wl (f16, unified 128B rows); r1 = x@wr + b (f32, in d_out) ----
  const int pb   = bx - 2 * NBKT;
  const int h    = (pb >= NBLK) ? 1 : 0;
  const int nblk = pb - (h ? NBLK : 0);
  const float* wl   = h ? w1_nl : w1_pl;  // [64][32]
  const float* wr   = h ? w1_nr : w1_pr;  // [64][32]
  const float* bias = h ? b1_n  : b1_p;

  float* s_wl = (float*)smem;           // [64*32]
  float* s_wr = (float*)smem + 2048;    // [64*32]
  for (int i = t; i < DIM * HH; i += 512) {
    s_wl[i] = wl[i];
    s_wr[i] = wr[i];
  }
  __syncthreads();

  int node = nblk * 512 + t;
  if (node >= NN) return;

  float ay[HH], ar[HH];
#pragma unroll
  for (int j = 0; j < HH; ++j) { ay[j] = 0.f; ar[j] = bias[j]; }

  const float4* xrow = (const float4*)(x + (size_t)node * DIM);
#pragma unroll 4
  for (int k4 = 0; k4 < DIM / 4; ++k4) {
    float4 xv = xrow[k4];
#pragma unroll
    for (int u = 0; u < 4; ++u) {
      int k = k4 * 4 + u;
      float xk = (&xv.x)[u];
#pragma unroll
      for (int j = 0; j < HH; ++j) {
        ay[j] += xk * s_wl[k * HH + j];
        ar[j] += xk * s_wr[k * HH + j];
      }
    }
  }

  uint*  yo = y1u + (size_t)node * 32 + h * 16;
  float* ro = r1  + (size_t)node * 64 + h * 32;
#pragma unroll
  for (int j = 0; j < 16; ++j) yo[j] = pk16(ay[2 * j], ay[2 * j + 1]);
#pragma unroll
  for (int j = 0; j < HH; ++j) ro[j] = ar[j];
}

// ---------------- aggregation 1 (16 edges/iter, uint4 per lane) ----------------
// y1 row = 32 uints: [pos 0..15 | neg 16..31]. lane = (g,f): g=lane>>2 (16 edge
// slots), f=lane&3. Lane loads uint4 = features 8f..8f+7 of its half.
// NOTE: r1 and z ALIAS (both d_out): same-thread read-then-write only.
__global__ void k_aggr1(const uint* __restrict__ y1u,
                        const int* __restrict__ rp, const int* __restrict__ cp,
                        const int* __restrict__ rn, const int* __restrict__ cn,
                        const float* r1,
                        float* z) {
  int gid  = blockIdx.x * 256 + threadIdx.x;
  int node = gid >> 6;
  if (node >= NN) return;
  int lane = threadIdx.x & 63;
  int g = lane >> 2;      // edge slot 0..15
  int f = lane & 3;       // uint4 index within a 16-uint half

  int s = rp[node], e = rp[node + 1];
  float a[8];
#pragma unroll
  for (int j = 0; j < 8; ++j) a[j] = 0.f;
  for (int i = s + g; i < e; i += 16) {
    int c = cp[i];
    uint4 v = *(const uint4*)&y1u[(size_t)c * 32 + 4 * f];
    float2 p0 = up16(v.x), p1 = up16(v.y), p2 = up16(v.z), p3 = up16(v.w);
    a[0] += p0.x; a[1] += p0.y; a[2] += p1.x; a[3] += p1.y;
    a[4] += p2.x; a[5] += p2.y; a[6] += p3.x; a[7] += p3.y;
  }
#pragma unroll
  for (int w = 4; w <= 32; w <<= 1) {
#pragma unroll
    for (int j = 0; j < 8; ++j) a[j] += __shfl_xor(a[j], w);
  }
  float invp = 1.f / (float)max(e - s, 1);

  s = rn[node]; e = rn[node + 1];
  float b[8];
#pragma unroll
  for (int j = 0; j < 8; ++j) b[j] = 0.f;
  for (int i = s + g; i < e; i += 16) {
    int c = cn[i];
    uint4 v = *(const uint4*)&y1u[(size_t)c * 32 + 16 + 4 * f];
    float2 p0 = up16(v.x), p1 = up16(v.y), p2 = up16(v.z), p3 = up16(v.w);
    b[0] += p0.x; b[1] += p0.y; b[2] += p1.x; b[3] += p1.y;
    b[4] += p2.x; b[5] += p2.y; b[6] += p3.x; b[7] += p3.y;
  }
#pragma unroll
  for (int w = 4; w <= 32; w <<= 1) {
#pragma unroll
    for (int j = 0; j < 8; ++j) b[j] += __shfl_xor(b[j], w);
  }
  float invn = 1.f / (float)max(e - s, 1);

  size_t base = (size_t)node * 64;
  if (g == 0) {
    const float4 r0 = *(const float4*)(r1 + base + 8 * f);
    const float4 r1v = *(const float4*)(r1 + base + 8 * f + 4);
    float4 o0, o1;
    o0.x = fmaxf(a[0] * invp + r0.x, 0.f);
    o0.y = fmaxf(a[1] * invp + r0.y, 0.f);
    o0.z = fmaxf(a[2] * invp + r0.z, 0.f);
    o0.w = fmaxf(a[3] * invp + r0.w, 0.f);
    o1.x = fmaxf(a[4] * invp + r1v.x, 0.f);
    o1.y = fmaxf(a[5] * invp + r1v.y, 0.f);
    o1.z = fmaxf(a[6] * invp + r1v.z, 0.f);
    o1.w = fmaxf(a[7] * invp + r1v.w, 0.f);
    *(float4*)(z + base + 8 * f) = o0;
    *(float4*)(z + base + 8 * f + 4) = o1;
  } else if (g == 1) {
    const float4 r0 = *(const float4*)(r1 + base + 32 + 8 * f);
    const float4 r1v = *(const float4*)(r1 + base + 32 + 8 * f + 4);
    float4 o0, o1;
    o0.x = fmaxf(b[0] * invn + r0.x, 0.f);
    o0.y = fmaxf(b[1] * invn + r0.y, 0.f);
    o0.z = fmaxf(b[2] * invn + r0.z, 0.f);
    o0.w = fmaxf(b[3] * invn + r0.w, 0.f);
    o1.x = fmaxf(b[4] * invn + r1v.x, 0.f);
    o1.y = fmaxf(b[5] * invn + r1v.y, 0.f);
    o1.z = fmaxf(b[6] * invn + r1v.z, 0.f);
    o1.w = fmaxf(b[7] * invn + r1v.w, 0.f);
    *(float4*)(z + base + 32 + 8 * f) = o0;
    *(float4*)(z + base + 32 + 8 * f + 4) = o1;
  }
}

// ---------------- pre-transform layer 2 ----------------
__global__ void k_mid(const float* __restrict__ z,
                      const float* __restrict__ w2_pl, const float* __restrict__ w2_pr,
                      const float* __restrict__ b2_p,
                      const float* __restrict__ w2_nl, const float* __restrict__ w2_nr,
                      const float* __restrict__ b2_n,
                      uint* __restrict__ u_pos, uint* __restrict__ u_neg,
                      float* __restrict__ r2) {
  const int t = blockIdx.y;
  const float* mat;
  const float* bias = nullptr;
  int srcHalf;            // 0 = zp, 1 = zn
  switch (t) {
    case 0: mat = w2_pl;            srcHalf = 0; break;
    case 1: mat = w2_nl;            srcHalf = 1; break;
    case 2: mat = w2_pl + 32 * 32;  srcHalf = 1; break;
    case 3: mat = w2_nl + 32 * 32;  srcHalf = 0; break;
    case 4: mat = w2_pr; bias = b2_p; srcHalf = 0; break;
    default: mat = w2_nr; bias = b2_n; srcHalf = 1; break;
  }

  __shared__ float s_m[HH][HH];
  for (int i = threadIdx.x; i < HH * HH; i += 256) s_m[i >> 5][i & 31] = mat[i];
  __syncthreads();

  int node = blockIdx.x * 256 + threadIdx.x;
  if (node >= NN) return;

  float acc[HH];
#pragma unroll
  for (int j = 0; j < HH; ++j) acc[j] = bias ? bias[j] : 0.f;

  const float4* zrow = (const float4*)(z + (size_t)node * 64 + srcHalf * 32);
#pragma unroll 4
  for (int k4 = 0; k4 < HH / 4; ++k4) {
    float4 v = zrow[k4];
#pragma unroll
    for (int u = 0; u < 4; ++u) {
      int k = k4 * 4 + u;
      float vv = (&v.x)[u];
#pragma unroll
      for (int j = 0; j < HH; ++j) acc[j] += vv * s_m[k][j];
    }
  }

  if (t < 4) {
    uint* o = (t < 2 ? u_pos : u_neg) + (size_t)node * 32 + (t & 1) * 16;
#pragma unroll
    for (int j = 0; j < 16; ++j) o[j] = pk16(acc[2 * j], acc[2 * j + 1]);
  } else {
    float* o = r2 + (size_t)node * 64 + (t - 4) * 32;
#pragma unroll
    for (int j = 0; j < HH; ++j) o[j] = acc[j];
  }
}

// ---------------- aggregation 2 (8 edges/iter, uint4 per lane) ----------------
__global__ void k_aggr2(const uint* __restrict__ u_pos, const uint* __restrict__ u_neg,
                        const int* __restrict__ rp, const int* __restrict__ cp,
                        const int* __restrict__ rn, const int* __restrict__ cn,
                        const float* __restrict__ r2,
                        float* __restrict__ out) {
  int gid  = blockIdx.x * 256 + threadIdx.x;
  int node = gid >> 6;
  if (node >= NN) return;
  int lane = threadIdx.x & 63;
  int g = lane >> 3;      // edge slot 0..7
  int f = lane & 7;       // uint4 index in row

  int s = rp[node], e = rp[node + 1];
  float a[8];
#pragma unroll
  for (int j = 0; j < 8; ++j) a[j] = 0.f;
  for (int i = s + g; i < e; i += 8) {
    int c = cp[i];
    uint4 v = *(const uint4*)&u_pos[(size_t)c * 32 + 4 * f];
    float2 p0 = up16(v.x), p1 = up16(v.y), p2 = up16(v.z), p3 = up16(v.w);
    a[0] += p0.x; a[1] += p0.y; a[2] += p1.x; a[3] += p1.y;
    a[4] += p2.x; a[5] += p2.y; a[6] += p3.x; a[7] += p3.y;
  }
#pragma unroll
  for (int w = 8; w <= 32; w <<= 1) {
#pragma unroll
    for (int j = 0; j < 8; ++j) a[j] += __shfl_xor(a[j], w);
  }
  float invp = 1.f / (float)max(e - s, 1);

  s = rn[node]; e = rn[node + 1];
  float b[8];
#pragma unroll
  for (int j = 0; j < 8; ++j) b[j] = 0.f;
  for (int i = s + g; i < e; i += 8) {
    int c = cn[i];
    uint4 v = *(const uint4*)&u_neg[(size_t)c * 32 + 4 * f];
    float2 p0 = up16(v.x), p1 = up16(v.y), p2 = up16(v.z), p3 = up16(v.w);
    b[0] += p0.x; b[1] += p0.y; b[2] += p1.x; b[3] += p1.y;
    b[4] += p2.x; b[5] += p2.y; b[6] += p3.x; b[7] += p3.y;
  }
#pragma unroll
  for (int w = 8; w <= 32; w <<= 1) {
#pragma unroll
    for (int j = 0; j < 8; ++j) b[j] += __shfl_xor(b[j], w);
  }
  float invn = 1.f / (float)max(e - s, 1);

  if (g == 0) {
    size_t base = (size_t)node * 64 + 8 * f;
    const float4 r0 = *(const float4*)(r2 + base);
    const float4 r1v = *(const float4*)(r2 + base + 4);
    float4 o0, o1;
    o0.x = fmaxf(a[0] * invp + b[0] * invn + r0.x, 0.f);
    o0.y = fmaxf(a[1] * invp + b[1] * invn + r0.y, 0.f);
    o0.z = fmaxf(a[2] * invp + b[2] * invn + r0.z, 0.f);
    o0.w = fmaxf(a[3] * invp + b[3] * invn + r0.w, 0.f);
    o1.x = fmaxf(a[4] * invp + b[4] * invn + r1v.x, 0.f);
    o1.y = fmaxf(a[5] * invp + b[5] * invn + r1v.y, 0.f);
    o1.z = fmaxf(a[6] * invp + b[6] * invn + r1v.z, 0.f);
    o1.w = fmaxf(a[7] * invp + b[7] * invn + r1v.w, 0.f);
    *(float4*)(out + base) = o0;
    *(float4*)(out + base + 4) = o1;
  }
}

// ---------------- launch ----------------

extern "C" void kernel_launch(void* const* d_in, const int* in_sizes, int n_in,
                              void* d_out, int out_size, void* d_ws, size_t ws_size,
                              hipStream_t stream) {
  const float* x     = (const float*)d_in[0];
  const int*   pe    = (const int*)d_in[1];
  const int*   ne    = (const int*)d_in[2];
  const float* w1_pl = (const float*)d_in[3];
  const float* w1_pr = (const float*)d_in[4];
  const float* b1_p  = (const float*)d_in[5];
  const float* w1_nl = (const float*)d_in[6];
  const float* w1_nr = (const float*)d_in[7];
  const float* b1_n  = (const float*)d_in[8];
  const float* w2_pl = (const float*)d_in[9];
  const float* w2_pr = (const float*)d_in[10];
  const float* b2_p  = (const float*)d_in[11];
  const float* w2_nl = (const float*)d_in[12];
  const float* w2_nr = (const float*)d_in[13];
  const float* b2_n  = (const float*)d_in[14];

  char* ws = (char*)d_ws;
  size_t off = 0;
  auto alloc = [&](size_t bytes) -> char* {
    char* p = ws + off;
    off = (off + bytes + 255) & ~(size_t)255;
    return p;
  };

  int* row_p = (int*)alloc((size_t)(NN + 1) * 4);
  int* row_n = (int*)alloc((size_t)(NN + 1) * 4);
  int* col_p = (int*)alloc((size_t)NE * 4);
  int* col_n = (int*)alloc((size_t)NE * 4);
  int* part_hist = (int*)alloc((size_t)2 * HB * 256 * 4);  // 512KB
  int* tot   = (int*)alloc((size_t)2 * 256 * 4);
  int* base  = (int*)alloc((size_t)2 * 257 * 4);

  // union region A (25.6MB): packed partition arrays (c_scatter..c_bucket, 12.8MB)
  //                        / u_pos+u_neg (k_mid..k_aggr2, 25.6MB)
  char* regA  = alloc((size_t)NN * 64 * 4);
  uint* partP = (uint*)regA;
  uint* partN = (uint*)(regA + (size_t)NE * 4);
  uint* u_pos = (uint*)regA;
  uint* u_neg = (uint*)(regA + (size_t)NN * 32 * 4);

  // union region B (25.6MB): y1 (c_bucket..k_aggr1, 12.8MB) / r2 (k_mid..k_aggr2)
  char*  regB = alloc((size_t)NN * 64 * 4);
  uint*  y1u  = (uint*)regB;
  float* r2   = (float*)regB;

  // r1 and z both live in d_out; k_aggr2 fully overwrites d_out at the end.
  float* r1 = (float*)d_out;
  float* z  = (float*)d_out;

  const int nb = (NN + 255) / 256;
  const int ab = (NN * 64 + 255) / 256;

  dim3 hg(HB, 2);
  c_hist<<<hg, 256, 0, stream>>>(pe, ne, part_hist);
  dim3 cg(256, 2);
  c_colscan<<<cg, 256, 0, stream>>>(part_hist, tot);
  c_basescan<<<1, 512, 0, stream>>>(tot, base);
  c_scatter<<<hg, 256, 0, stream>>>(pe, ne, part_hist, base, partP, partN);
  c_bucket<<<2 * NBKT + 2 * NBLK, 512, 0, stream>>>(
      partP, partN, base, row_p, row_n, col_p, col_n,
      x, w1_pl, w1_pr, b1_p, w1_nl, w1_nr, b1_n, y1u, r1);

  k_aggr1<<<ab, 256, 0, stream>>>(y1u, row_p, col_p, row_n, col_n, r1, z);

  dim3 g2(nb, 6);
  k_mid<<<g2, 256, 0, stream>>>(z, w2_pl, w2_pr, b2_p, w2_nl, w2_nr, b2_n,
                                u_pos, u_neg, r2);

  k_aggr2<<<ab, 256, 0, stream>>>(u_pos, u_neg, row_p, col_p, row_n, col_n, r2,
                                  (float*)d_out);
}